// Round 1
// baseline (9.699 us; speedup 1.0000x reference)
//
#include <hip/hip_runtime.h>
#include <math.h>

// LSTM, one step, all dims == 1:
//   x: (1,1,1)  state_h: (1,1)  state_c: (1,1)
//   kernel: (1,4)  recurrent_kernel: (1,4)  bias: (4,)
// out: h_new (1,1) float32
//
// z[j] = x*kernel[j] + h*rkernel[j] + bias[j], j in {i,f,c,o}
// i=sig(z0) f=sig(z1) c_new=f*c + i*tanh(z2) o=sig(z3) h_new=o*tanh(c_new)

__device__ __forceinline__ float sigmoidf(float v) {
    return 1.0f / (1.0f + __expf(-v));
}

__global__ void lstm_scalar_kernel(const float* __restrict__ x,
                                   const float* __restrict__ h0,
                                   const float* __restrict__ c0,
                                   const float* __restrict__ k,
                                   const float* __restrict__ rk,
                                   const float* __restrict__ b,
                                   float* __restrict__ out) {
    if (threadIdx.x == 0) {
        const float xv = x[0];
        const float h  = h0[0];
        const float c  = c0[0];

        const float zi = fmaf(xv, k[0], fmaf(h, rk[0], b[0]));
        const float zf = fmaf(xv, k[1], fmaf(h, rk[1], b[1]));
        const float zc = fmaf(xv, k[2], fmaf(h, rk[2], b[2]));
        const float zo = fmaf(xv, k[3], fmaf(h, rk[3], b[3]));

        const float i  = sigmoidf(zi);
        const float f  = sigmoidf(zf);
        const float cn = f * c + i * tanhf(zc);
        const float o  = sigmoidf(zo);

        out[0] = o * tanhf(cn);
    }
}

extern "C" void kernel_launch(void* const* d_in, const int* in_sizes, int n_in,
                              void* d_out, int out_size, void* d_ws, size_t ws_size,
                              hipStream_t stream) {
    const float* x  = (const float*)d_in[0];
    const float* h0 = (const float*)d_in[1];
    const float* c0 = (const float*)d_in[2];
    const float* k  = (const float*)d_in[3];
    const float* rk = (const float*)d_in[4];
    const float* b  = (const float*)d_in[5];
    float* out = (float*)d_out;

    lstm_scalar_kernel<<<1, 64, 0, stream>>>(x, h0, c0, k, rk, b, out);
}